// Round 7
// baseline (91.788 us; speedup 1.0000x reference)
//
#include <hip/hip_runtime.h>

typedef short short8 __attribute__((ext_vector_type(8)));
typedef float floatx16 __attribute__((ext_vector_type(16)));

#define B_    4
#define NPTS  8192           // N == M == 8192
#define IS    64             // i-splits (128 src per block)
#define JS    4              // j-splits (2048 dst per block)
#define ITB   128
#define JTB   2048
#define NJT   (JTB / 32)     // 64 j-tiles per wave
#define TOT   (B_ * NPTS)    // 32768
#define ARR   32768          // granules per packed array (B_*NPTS)

// ws layout (R4/R6-proven pack): 8 granule arrays short8[ARR] (4 MB), then
// slots uint32[2*TOT] (256 KiB) at offset 8*ARR granules.
//   [0][1] A k0..7/k8..15 dir0 = pack_dst(gt)    [2][3] dir1 = pack_dst(pred)
//   [4][5] B k0..7/k8..15 dir0 = pack_src(pred)  [6][7] dir1 = pack_src(gt)
// A-array index = dir*2 + h;  B-array index = 4 + dir*2 + h.

__device__ __forceinline__ unsigned short bf16h(float v) {
  unsigned u = __float_as_uint(v);
  return (unsigned short)((u + 0x7FFFu + ((u >> 16) & 1u)) >> 16);   // RNE
}
__device__ __forceinline__ void bf16split(float v, unsigned short& h, unsigned short& l) {
  h = bf16h(v);
  l = bf16h(v - __uint_as_float((unsigned)h << 16));
}

// K-slot scheme (k0..15, all real) — byte-identical to R3/R6-proven:
//   A (dst j): k0..7  [axh axh axl axl  ayh ayh ayl ayl]      a = -2g
//              k8..15 [azh azh azl azl  wh  wl  1   1 ]       w = ||g||^2
//   B (src i): k0..7  [pxh pxl pxh pxl  pyh pyl pyh pyl]
//              k8..15 [pzh pzl pzh pzl  1   1   qh  ql]       q = ||p||^2
// Sum_k A[j][k]B[k][i] = -2<g,p> + ||g||^2 + ||p||^2 = squared distance.
__device__ __forceinline__ void pack_dst(const float* g, short8& s0, short8& s1) {
  const float x = g[0], y = g[1], z = g[2];
  const float w = fmaf(x, x, fmaf(y, y, z * z));
  unsigned short xh, xl, yh, yl, zh, zl, wh, wl;
  bf16split(-2.f * x, xh, xl); bf16split(-2.f * y, yh, yl);
  bf16split(-2.f * z, zh, zl); bf16split(w, wh, wl);
  s0 = (short8){(short)xh,(short)xh,(short)xl,(short)xl,
                (short)yh,(short)yh,(short)yl,(short)yl};
  s1 = (short8){(short)zh,(short)zh,(short)zl,(short)zl,
                (short)wh,(short)wl,(short)0x3F80,(short)0x3F80};
}
__device__ __forceinline__ void pack_src(const float* p, short8& s0, short8& s1) {
  const float x = p[0], y = p[1], z = p[2];
  const float qq = fmaf(x, x, fmaf(y, y, z * z));
  unsigned short xh, xl, yh, yl, zh, zl, qh, ql;
  bf16split(x, xh, xl); bf16split(y, yh, yl);
  bf16split(z, zh, zl); bf16split(qq, qh, ql);
  s0 = (short8){(short)xh,(short)xl,(short)xh,(short)xl,
                (short)yh,(short)yl,(short)yh,(short)yl};
  s1 = (short8){(short)zh,(short)zl,(short)zh,(short)zl,
                (short)0x3F80,(short)0x3F80,(short)qh,(short)ql};
}

// Pack every point once + init slots + out=0 (R6-proven).
__global__ __launch_bounds__(256) void pack_kernel(
    const float* __restrict__ pred, const float* __restrict__ gt,
    short8* __restrict__ W, unsigned* __restrict__ slots,
    float* __restrict__ out) {
  const int gid = blockIdx.x * 256 + threadIdx.x;   // 65536 threads
  slots[gid] = 0xFFFFFFFFu;
  if (gid == 0) out[0] = 0.f;
  const int cloud = gid >> 15;
  const int idx = gid & (ARR - 1);                  // b*NPTS + pt
  const float* p = (cloud ? gt : pred) + (size_t)idx * 3;
  short8 d0, d1, s0, s1;
  pack_dst(p, d0, d1);
  pack_src(p, s0, s1);
  if (cloud) {  // gt: dst for dir0, src for dir1
    W[0 * ARR + idx] = d0;  W[1 * ARR + idx] = d1;
    W[6 * ARR + idx] = s0;  W[7 * ARR + idx] = s1;
  } else {      // pred: dst for dir1, src for dir0
    W[2 * ARR + idx] = d0;  W[3 * ARR + idx] = d1;
    W[4 * ARR + idx] = s0;  W[5 * ARR + idx] = s1;
  }
}

// grid (IS, JS, 2*B_) = (64,4,8) = 2048 blocks, 256 thr (4 waves).
// Wave w owns ONE 32-i tile (i = ibase + w*32 .. +31) over all 2048 block-j.
// Lean loop: 1 live accumulator tile, distance-1 af prefetch, balanced
// fminf tree (depth 5; ISel may fuse min3).  launch_bounds(256,8) forces
// VGPR<=64 -> 8 blocks (32 waves) per CU for max TLP.
// atomicMin per (i, j-split): 128/block, 262k total (was 1M).
// mfma_f32_32x32x16_bf16 mapping (R3-proven):
//   A[row=j][k], B[k][col=i]; lane: n=lane&31 (point), h=lane>>5 (k-half);
//   D: col=lane&31, row=(reg&3)+8*(reg>>2)+4*(lane>>5).
// NO inline asm on MFMA outputs (R1/R2 lesson).
__global__ __launch_bounds__(256, 8) void mfma_pass_kernel(
    const short8* __restrict__ W, unsigned* __restrict__ slots) {
  const int zb  = blockIdx.z;
  const int dir = zb >> 2;
  const int b   = zb & 3;
  const int tid   = threadIdx.x;
  const int lane  = tid & 63;
  const int w     = tid >> 6;
  const int n     = lane & 31;   // point index within 32-tile (A: j, B: i)
  const int h     = lane >> 5;   // k-half: 0 -> k0..7, 1 -> k8..15
  const int jbase = blockIdx.y * JTB;
  const int ibase = blockIdx.x * ITB;

  const short8* Ap = W + (size_t)(dir * 2 + h) * ARR + (size_t)b * NPTS + jbase;
  const short8* Bp = W + (size_t)(4 + dir * 2 + h) * ARR + (size_t)b * NPTS + ibase;

  // B fragment: one direct load (32 lanes x 16 B contiguous per half).
  const short8 bf = Bp[w * 32 + n];

  float ma = 1e30f, mb = 1e30f;
  const floatx16 zero16 = {0.f,0.f,0.f,0.f, 0.f,0.f,0.f,0.f,
                           0.f,0.f,0.f,0.f, 0.f,0.f,0.f,0.f};

  short8 af = Ap[n];                         // jt = 0
  for (int jt = 0; jt < NJT; ++jt) {
    // Prefetch next tile's A fragment (branchless wrap; one redundant load).
    const short8 afn = Ap[((jt + 1) & (NJT - 1)) * 32 + n];
    floatx16 d = __builtin_amdgcn_mfma_f32_32x32x16_bf16(af, bf, zero16, 0, 0, 0);
    // Balanced min tree, depth 5: frees the accumulator tile fast.
    const float e0 = fminf(d[0],  d[1]),  e1 = fminf(d[2],  d[3]);
    const float e2 = fminf(d[4],  d[5]),  e3 = fminf(d[6],  d[7]);
    const float e4 = fminf(d[8],  d[9]),  e5 = fminf(d[10], d[11]);
    const float e6 = fminf(d[12], d[13]), e7 = fminf(d[14], d[15]);
    const float f0 = fminf(e0, e1), f1 = fminf(e2, e3);
    const float f2 = fminf(e4, e5), f3 = fminf(e6, e7);
    ma = fminf(ma, fminf(f0, f1));
    mb = fminf(mb, fminf(f2, f3));
    af = afn;
  }

  // Merge the two k-halves (lanes n, n+32 hold complementary j-rows of the
  // same column i=n), then ONE atomicMin per (i, block).  (R3-proven)
  float v = fminf(ma, mb);
  v = fminf(v, __shfl_xor(v, 32));
  if (lane < 32) {
    const int gi = ibase + w * 32 + lane;
    const int bi = __float_as_int(v);
    const unsigned u = (unsigned)bi ^ (unsigned)((bi >> 31) | 0x80000000);
    atomicMin(&slots[(size_t)(dir * B_ + b) * NPTS + gi], u);
  }
}

// Sweep 2*TOT slots, decode, reduce, one atomic per block.  (R3-proven)
__global__ __launch_bounds__(256) void pass2_kernel(
    const unsigned* __restrict__ slots, float* __restrict__ out) {
  const int gid = blockIdx.x * 256 + threadIdx.x;   // 8192 threads
  float s = 0.f;
#pragma unroll
  for (int k = 0; k < 8; ++k) {
    const unsigned u = slots[gid + k * 8192];
    const int bi = (u & 0x80000000u) ? (int)(u ^ 0x80000000u) : (int)~u;
    s += __int_as_float(bi);
  }
  __shared__ float red[256];
  const int tid = threadIdx.x;
  red[tid] = s;
  __syncthreads();
  for (int st = 128; st > 0; st >>= 1) {
    if (tid < st) red[tid] += red[tid + st];
    __syncthreads();
  }
  if (tid == 0) atomicAdd(out, red[0] * (1.0f / TOT));
}

extern "C" void kernel_launch(void* const* d_in, const int* in_sizes, int n_in,
                              void* d_out, int out_size, void* d_ws, size_t ws_size,
                              hipStream_t stream) {
  const float* pred = (const float*)d_in[0];
  const float* gt   = (const float*)d_in[1];
  short8* W = (short8*)d_ws;
  unsigned* slots = (unsigned*)(W + 8 * ARR);       // offset 4 MB, 256 KiB
  float* out = (float*)d_out;

  pack_kernel<<<(2 * ARR) / 256, 256, 0, stream>>>(pred, gt, W, slots, out);
  mfma_pass_kernel<<<dim3(IS, JS, 2 * B_), 256, 0, stream>>>(W, slots);
  pass2_kernel<<<(2 * TOT) / (256 * 8), 256, 0, stream>>>(slots, out);
}

// Round 8
// 77.042 us; speedup vs baseline: 1.1914x; 1.1914x over previous
//
#include <hip/hip_runtime.h>

typedef short short8 __attribute__((ext_vector_type(8)));
typedef float floatx16 __attribute__((ext_vector_type(16)));

#define B_    4
#define NPTS  8192           // N == M == 8192
#define IS    32             // i-splits (256 src per block)
#define JS    8              // j-splits (1024 dst per block)
#define ITB   256
#define JTB   1024
#define NT    2              // i-tiles (32 wide) per wave -> 64 i/wave
#define NJT   (JTB / 32)     // 32 j-tiles per block
#define TOT   (B_ * NPTS)    // 32768
#define ARR   32768          // granules per packed array (B_*NPTS)

// ws layout (R4/R6-proven pack): 8 granule arrays short8[ARR] (4 MB), then
// slots uint32[2*TOT] (256 KiB) at offset 8*ARR granules.
//   [0][1] A k0..7/k8..15 dir0 = pack_dst(gt)    [2][3] dir1 = pack_dst(pred)
//   [4][5] B k0..7/k8..15 dir0 = pack_src(pred)  [6][7] dir1 = pack_src(gt)
// A-array index = dir*2 + h;  B-array index = 4 + dir*2 + h.

__device__ __forceinline__ unsigned short bf16h(float v) {
  unsigned u = __float_as_uint(v);
  return (unsigned short)((u + 0x7FFFu + ((u >> 16) & 1u)) >> 16);   // RNE
}
__device__ __forceinline__ void bf16split(float v, unsigned short& h, unsigned short& l) {
  h = bf16h(v);
  l = bf16h(v - __uint_as_float((unsigned)h << 16));
}

// K-slot scheme (k0..15, all real) — byte-identical to R3/R6-proven:
//   A (dst j): k0..7  [axh axh axl axl  ayh ayh ayl ayl]      a = -2g
//              k8..15 [azh azh azl azl  wh  wl  1   1 ]       w = ||g||^2
//   B (src i): k0..7  [pxh pxl pxh pxl  pyh pyl pyh pyl]
//              k8..15 [pzh pzl pzh pzl  1   1   qh  ql]       q = ||p||^2
// Sum_k A[j][k]B[k][i] = -2<g,p> + ||g||^2 + ||p||^2 = squared distance.
__device__ __forceinline__ void pack_dst(const float* g, short8& s0, short8& s1) {
  const float x = g[0], y = g[1], z = g[2];
  const float w = fmaf(x, x, fmaf(y, y, z * z));
  unsigned short xh, xl, yh, yl, zh, zl, wh, wl;
  bf16split(-2.f * x, xh, xl); bf16split(-2.f * y, yh, yl);
  bf16split(-2.f * z, zh, zl); bf16split(w, wh, wl);
  s0 = (short8){(short)xh,(short)xh,(short)xl,(short)xl,
                (short)yh,(short)yh,(short)yl,(short)yl};
  s1 = (short8){(short)zh,(short)zh,(short)zl,(short)zl,
                (short)wh,(short)wl,(short)0x3F80,(short)0x3F80};
}
__device__ __forceinline__ void pack_src(const float* p, short8& s0, short8& s1) {
  const float x = p[0], y = p[1], z = p[2];
  const float qq = fmaf(x, x, fmaf(y, y, z * z));
  unsigned short xh, xl, yh, yl, zh, zl, qh, ql;
  bf16split(x, xh, xl); bf16split(y, yh, yl);
  bf16split(z, zh, zl); bf16split(qq, qh, ql);
  s0 = (short8){(short)xh,(short)xl,(short)xh,(short)xl,
                (short)yh,(short)yl,(short)yh,(short)yl};
  s1 = (short8){(short)zh,(short)zl,(short)zh,(short)zl,
                (short)0x3F80,(short)0x3F80,(short)qh,(short)ql};
}

// Pack every point once + init slots + out=0 (R6-proven).
__global__ __launch_bounds__(256) void pack_kernel(
    const float* __restrict__ pred, const float* __restrict__ gt,
    short8* __restrict__ W, unsigned* __restrict__ slots,
    float* __restrict__ out) {
  const int gid = blockIdx.x * 256 + threadIdx.x;   // 65536 threads
  slots[gid] = 0xFFFFFFFFu;
  if (gid == 0) out[0] = 0.f;
  const int cloud = gid >> 15;
  const int idx = gid & (ARR - 1);                  // b*NPTS + pt
  const float* p = (cloud ? gt : pred) + (size_t)idx * 3;
  short8 d0, d1, s0, s1;
  pack_dst(p, d0, d1);
  pack_src(p, s0, s1);
  if (cloud) {  // gt: dst for dir0, src for dir1
    W[0 * ARR + idx] = d0;  W[1 * ARR + idx] = d1;
    W[6 * ARR + idx] = s0;  W[7 * ARR + idx] = s1;
  } else {      // pred: dst for dir1, src for dir0
    W[2 * ARR + idx] = d0;  W[3 * ARR + idx] = d1;
    W[4 * ARR + idx] = s0;  W[5 * ARR + idx] = s1;
  }
}

// grid (IS, JS, 2*B_) = (32,8,8) = 2048 blocks, 256 thr (4 waves) — R6's
// proven structure with NT 4->2: arch-VGPR pressure ~80 so the MFMA
// accumulators stay in ARCH VGPRs (no v_accvgpr_read moves in the fold —
// the R0-counter-diagnosed VALU tax: VGPR_Count=52 + VALUBusy/MfmaUtil=2.4
// meant d lived in AGPRs and every fold paid per-element move-outs).
// launch_bounds(256,4): <=128 VGPR, no spill (R7's (256,8) spilled).
// mfma_f32_32x32x16_bf16 mapping (R3-proven):
//   A[row=j][k], B[k][col=i]; lane: n=lane&31 (point), h=lane>>5 (k-half);
//   D: col=lane&31, row=(reg&3)+8*(reg>>2)+4*(lane>>5).
// NO inline asm on MFMA outputs (R1/R2 lesson); nested fminf fuses to min3.
__global__ __launch_bounds__(256, 4) void mfma_pass_kernel(
    const short8* __restrict__ W, unsigned* __restrict__ slots) {
  const int zb  = blockIdx.z;
  const int dir = zb >> 2;
  const int b   = zb & 3;
  const int tid   = threadIdx.x;
  const int lane  = tid & 63;
  const int w     = tid >> 6;
  const int n     = lane & 31;   // point index within 32-tile (A: j, B: i)
  const int h     = lane >> 5;   // k-half: 0 -> k0..7, 1 -> k8..15
  const int jbase = blockIdx.y * JTB;
  const int ibase = blockIdx.x * ITB;

  const short8* Ap = W + (size_t)(dir * 2 + h) * ARR + (size_t)b * NPTS + jbase;
  const short8* Bp = W + (size_t)(4 + dir * 2 + h) * ARR + (size_t)b * NPTS + ibase;

  // B fragments: one direct load each (32 lanes x 16 B contiguous per half).
  short8 bf[NT];
  float  ma[NT], mb[NT];         // two independent min chains per tile
#pragma unroll
  for (int t = 0; t < NT; ++t) {
    bf[t] = Bp[w * (NT * 32) + t * 32 + n];
    ma[t] = 1e30f;
    mb[t] = 1e30f;
  }

  const floatx16 zero16 = {0.f,0.f,0.f,0.f, 0.f,0.f,0.f,0.f,
                           0.f,0.f,0.f,0.f, 0.f,0.f,0.f,0.f};

#pragma unroll 4
  for (int jt = 0; jt < NJT; ++jt) {
    const short8 af = Ap[jt * 32 + n];
#pragma unroll
    for (int t = 0; t < NT; ++t) {
      floatx16 d = __builtin_amdgcn_mfma_f32_32x32x16_bf16(af, bf[t], zero16, 0, 0, 0);
      // Two independent 8-value chains; min(min(a,b),c) nests fuse to min3.
      float ca = fminf(fminf(d[0], d[1]), d[2]);
      ca = fminf(fminf(ca, d[3]), d[4]);
      ca = fminf(fminf(ca, d[5]), d[6]);
      ma[t] = fminf(fminf(ca, d[7]), ma[t]);
      float cb = fminf(fminf(d[8], d[9]), d[10]);
      cb = fminf(fminf(cb, d[11]), d[12]);
      cb = fminf(fminf(cb, d[13]), d[14]);
      mb[t] = fminf(fminf(cb, d[15]), mb[t]);
    }
  }

  // Merge the two k-halves (lanes n, n+32 hold complementary j-rows of the
  // same column i=n), then ONE atomicMin per (i, block).  (R3-proven)
#pragma unroll
  for (int t = 0; t < NT; ++t) {
    float v = fminf(ma[t], mb[t]);
    v = fminf(v, __shfl_xor(v, 32));
    if (lane < 32) {
      const int gi = ibase + w * (NT * 32) + t * 32 + lane;
      const int bi = __float_as_int(v);
      const unsigned u = (unsigned)bi ^ (unsigned)((bi >> 31) | 0x80000000);
      atomicMin(&slots[(size_t)(dir * B_ + b) * NPTS + gi], u);
    }
  }
}

// Sweep 2*TOT slots, decode, reduce, one atomic per block.  (R3-proven)
__global__ __launch_bounds__(256) void pass2_kernel(
    const unsigned* __restrict__ slots, float* __restrict__ out) {
  const int gid = blockIdx.x * 256 + threadIdx.x;   // 8192 threads
  float s = 0.f;
#pragma unroll
  for (int k = 0; k < 8; ++k) {
    const unsigned u = slots[gid + k * 8192];
    const int bi = (u & 0x80000000u) ? (int)(u ^ 0x80000000u) : (int)~u;
    s += __int_as_float(bi);
  }
  __shared__ float red[256];
  const int tid = threadIdx.x;
  red[tid] = s;
  __syncthreads();
  for (int st = 128; st > 0; st >>= 1) {
    if (tid < st) red[tid] += red[tid + st];
    __syncthreads();
  }
  if (tid == 0) atomicAdd(out, red[0] * (1.0f / TOT));
}

extern "C" void kernel_launch(void* const* d_in, const int* in_sizes, int n_in,
                              void* d_out, int out_size, void* d_ws, size_t ws_size,
                              hipStream_t stream) {
  const float* pred = (const float*)d_in[0];
  const float* gt   = (const float*)d_in[1];
  short8* W = (short8*)d_ws;
  unsigned* slots = (unsigned*)(W + 8 * ARR);       // offset 4 MB, 256 KiB
  float* out = (float*)d_out;

  pack_kernel<<<(2 * ARR) / 256, 256, 0, stream>>>(pred, gt, W, slots, out);
  mfma_pass_kernel<<<dim3(IS, JS, 2 * B_), 256, 0, stream>>>(W, slots);
  pass2_kernel<<<(2 * TOT) / (256 * 8), 256, 0, stream>>>(slots, out);
}